// Round 11
// baseline (154.366 us; speedup 1.0000x reference)
//
#include <hip/hip_runtime.h>
#include <stdint.h>

// R11. Post-mortem R10 (151.6us): finalize split worked (~45->5us) but
// 2-phase dbuf only got k_stats 55.6->46.9us (MfmaUtil 6.5%, VALUBusy 15%).
// Mechanism: NBUF=2 forces vmcnt(0) on the JUST-issued stage each step;
// compute (~300cy) < load latency (~500-900cy) -> stall every K-step.
// Fix (T4, counted vmcnt): BK=32, NBUF=4, prefetch 3 ahead, steady-state
// wait vmcnt(8) (2 stages in flight across the barrier, never drain in-loop).
// Buffer-overwrite safety: stage(ks+3) hits buf (ks-1)&3; the iter-ks barrier
// guarantees all waves completed compute(ks-1) (ds_reads consumed by MFMA ->
// lgkm drained before barrier). LDS 4x16KB=64KB, 2 blocks/CU unchanged.
// Everything else unchanged from R10 (validated): bf16 sim, 528 upper-tri
// 128x128 tiles + dual epilogues, write-once partials, no atomics/memsets,
// nz == (S != 0), softplus(log S) = log1p(S), finalize split.

#define BS 4096
#define DIM 512
#define NTILES 528
#define NSLOT 32
#define NK 16                 // 512 / BK
#define BK 32
#define BUF_USH 8192          // per buffer: A 128x32 + B 128x32 ushorts (16 KB)
#define PANEL_USH 4096        // 128x32

typedef __attribute__((ext_vector_type(8))) short short8;
typedef __attribute__((ext_vector_type(4))) float f32x4;

// ---- helpers -------------------------------------------------------------
__device__ __forceinline__ ushort f2bf(float f){             // RNE fp32->bf16
  unsigned u = __float_as_uint(f);
  return (ushort)((u + 0x7fffu + ((u >> 16) & 1u)) >> 16);
}
__device__ __forceinline__ void gld_lds16(void* ldsp, const void* gp){
  __builtin_amdgcn_global_load_lds((const __attribute__((address_space(1))) void*)gp,
                                   (__attribute__((address_space(3))) void*)ldsp, 16, 0, 0);
}

// ---- K0: fp32 -> bf16 ----------------------------------------------------
__global__ void k_convert(const float* __restrict__ x, ushort* __restrict__ xh){
  int i = blockIdx.x * blockDim.x + threadIdx.x;   // over BS*DIM/4
  float4 v = ((const float4*)x)[i];
  ((ushort4*)xh)[i] = make_ushort4(f2bf(v.x), f2bf(v.y), f2bf(v.z), f2bf(v.w));
}

// ---- tile decode: 528 upper-tri tiles, XCD-swizzled (528 = 8*66) ---------
__device__ __forceinline__ void decode_tile(int bid, int& Rm, int& Rn, bool& diag){
  int wg = (bid & 7) * 66 + (bid >> 3);
  int ii = wg, bm = 0;
  while (ii >= 32 - bm){ ii -= 32 - bm; ++bm; }
  const int bn = bm + ii;
  diag = (bm == bn);
  Rm = bm * 128; Rn = bn * 128;
}

// ---- staging: one BK=32 K-step of A and B panels into buffer b -----------
// slot s = rep*256 + t; LDS linear offset 16B*s (gld_lds requirement);
// logical LDS[row = s>>2][g = s&3] holds global col-group g ^ (row&3).
__device__ __forceinline__ void stage_ks(ushort* buf,
                                         const ushort* __restrict__ gA,
                                         const ushort* __restrict__ gB,
                                         int ks, int t){
  const int gx = (t & 3) ^ ((t >> 2) & 3);    // source col-group (involution)
  const int kb = ks * BK + gx * 8;
  #pragma unroll
  for (int rep = 0; rep < 2; ++rep){
    const int row = rep * 64 + (t >> 2);
    const int lo  = (rep * 256 + t) * 8;
    gld_lds16(buf + lo,             gA + (size_t)row * DIM + kb);
    gld_lds16(buf + PANEL_USH + lo, gB + (size_t)row * DIM + kb);
  }
}

// ---- GEMM core: 4-buffer, prefetch-3, counted-vmcnt pipeline (T4) --------
__device__ __forceinline__ void gemm_tile_pipe(f32x4 (&acc)[4][4],
                                               ushort (&lds)[4][BUF_USH],
                                               const ushort* __restrict__ Xh,
                                               int Rm, int Rn, int t)
{
  const int l  = t & 63;
  const int w  = t >> 6;
  const int wm = w >> 1, wn = w & 1;
  const int lc = l & 15;
  const int lq = l >> 4;
  const ushort* gA = Xh + (size_t)Rm * DIM;
  const ushort* gB = Xh + (size_t)Rn * DIM;

  #pragma unroll
  for (int i = 0; i < 4; ++i)
    #pragma unroll
    for (int j = 0; j < 4; ++j) acc[i][j] = (f32x4){0.f, 0.f, 0.f, 0.f};

  // prologue: 3 stages in flight (12 loads/thread)
  stage_ks(&lds[0][0], gA, gB, 0, t);
  stage_ks(&lds[1][0], gA, gB, 1, t);
  stage_ks(&lds[2][0], gA, gB, 2, t);

  #pragma unroll
  for (int ks = 0; ks < NK; ++ks){
    // wait only the OLDEST stage (ks); keep later stages in flight
    if (ks < NK - 2)      asm volatile("s_waitcnt vmcnt(8)" ::: "memory");
    else if (ks == NK-2)  asm volatile("s_waitcnt vmcnt(4)" ::: "memory");
    else                  asm volatile("s_waitcnt vmcnt(0)" ::: "memory");
    __builtin_amdgcn_s_barrier();         // all waves' stage(ks) complete;
    __builtin_amdgcn_sched_barrier(0);    // all waves done computing ks-1
    if (ks + 3 < NK)
      stage_ks(&lds[(ks + 3) & 3][0], gA, gB, ks + 3, t);   // reuses buf (ks-1)&3
    const ushort* buf = &lds[ks & 3][0];
    const int sl = (lq ^ (lc & 3)) * 8;   // read-side involution (row&3 == lc&3)
    short8 ah[4], bh[4];
    #pragma unroll
    for (int f = 0; f < 4; ++f){
      ah[f] = *(const short8*)&buf[(wm * 64 + f * 16 + lc) * BK + sl];
      bh[f] = *(const short8*)&buf[PANEL_USH + (wn * 64 + f * 16 + lc) * BK + sl];
    }
    #pragma unroll
    for (int fm = 0; fm < 4; ++fm)
      #pragma unroll
      for (int fn = 0; fn < 4; ++fn)
        acc[fm][fn] = __builtin_amdgcn_mfma_f32_16x16x32_bf16(ah[fm], bh[fn], acc[fm][fn], 0, 0, 0);
    __builtin_amdgcn_sched_barrier(0);
  }
}

// ---- K1: GEMM + per-row bound PARTIALS -----------------------------------
// posB/negB float[NSLOT][BS]; for row-tile r: slot s>=r by std of tile (r,s)
// (diag incl.), slot s<r by transposed of tile (s,r). Each written once.
__global__ __launch_bounds__(256)
void k_bounds(const ushort* __restrict__ Xh, const int* __restrict__ labels,
              float* __restrict__ posB, float* __restrict__ negB)
{
  __shared__ ushort lds[4][BUF_USH];
  const int t = threadIdx.x;
  int Rm, Rn; bool diag;
  decode_tile((int)blockIdx.x, Rm, Rn, diag);
  const int bm = Rm >> 7, bn = Rn >> 7;

  f32x4 acc[4][4];
  gemm_tile_pipe(acc, lds, Xh, Rm, Rn, t);

  const int l  = t & 63;
  const int w  = t >> 6;
  const int wm = w >> 1, wn = w & 1;
  const int lc = l & 15, lq = l >> 4;
  const float INF = __builtin_inff();

  int labr[4][4];
  #pragma unroll
  for (int fm = 0; fm < 4; ++fm)
    #pragma unroll
    for (int v = 0; v < 4; ++v)
      labr[fm][v] = labels[Rm + wm * 64 + fm * 16 + lq * 4 + v];

  // LDS scratch aliases buffer 0 (dead after K-loop); full sync first
  __syncthreads();
  float* sMnS = (float*)&lds[0][0];   // [wm][wn][r64] std per-row min
  float* sMxS = sMnS + 256;           // std per-row max
  float* sMnT = sMnS + 512;           // [wn][wm][c64] transposed min
  float* sMxT = sMnS + 768;           // transposed max

  // std: bounds for rows of Rm-block over this wave's 64 cols
  #pragma unroll
  for (int fm = 0; fm < 4; ++fm){
    float mn[4] = {INF, INF, INF, INF};
    float mx[4] = {-INF, -INF, -INF, -INF};
    #pragma unroll
    for (int fn = 0; fn < 4; ++fn){
      const int gc = Rn + wn * 64 + fn * 16 + lc;
      const int labc = labels[gc];
      #pragma unroll
      for (int v = 0; v < 4; ++v){
        const float s = acc[fm][fn][v];
        const int grow = Rm + wm * 64 + fm * 16 + lq * 4 + v;
        const bool same = (labc == labr[fm][v]);
        mn[v] = fminf(mn[v], (same && (grow != gc)) ? s : INF);
        mx[v] = fmaxf(mx[v], same ? -INF : s);
      }
    }
    #pragma unroll
    for (int off = 1; off < 16; off <<= 1)
      #pragma unroll
      for (int v = 0; v < 4; ++v){
        mn[v] = fminf(mn[v], __shfl_xor(mn[v], off));
        mx[v] = fmaxf(mx[v], __shfl_xor(mx[v], off));
      }
    if (lc == 0){
      #pragma unroll
      for (int v = 0; v < 4; ++v){
        const int r64 = fm * 16 + lq * 4 + v;
        sMnS[(wm * 2 + wn) * 64 + r64] = mn[v];
        sMxS[(wm * 2 + wn) * 64 + r64] = mx[v];
      }
    }
  }
  if (!diag){
    // transposed: bounds for rows == this tile's column indices
    #pragma unroll
    for (int fn = 0; fn < 4; ++fn){
      const int gc = Rn + wn * 64 + fn * 16 + lc;
      const int labc = labels[gc];
      float mn = INF, mx = -INF;
      #pragma unroll
      for (int fm = 0; fm < 4; ++fm)
        #pragma unroll
        for (int v = 0; v < 4; ++v){
          const float s = acc[fm][fn][v];
          const bool same = (labc == labr[fm][v]);
          mn = fminf(mn, same ? s : INF);        // grow != gc off-diagonal
          mx = fmaxf(mx, same ? -INF : s);
        }
      #pragma unroll
      for (int off = 16; off < 64; off <<= 1){
        mn = fminf(mn, __shfl_xor(mn, off));
        mx = fmaxf(mx, __shfl_xor(mx, off));
      }
      if (l < 16){
        const int c64 = fn * 16 + lc;
        sMnT[(wn * 2 + wm) * 64 + c64] = mn;
        sMxT[(wn * 2 + wm) * 64 + c64] = mx;
      }
    }
  }
  __syncthreads();
  if (t < 128){
    const int h = t >> 6, r = t & 63;
    posB[(size_t)bn * BS + Rm + t] = fminf(sMnS[(h * 2 + 0) * 64 + r], sMnS[(h * 2 + 1) * 64 + r]);
    negB[(size_t)bn * BS + Rm + t] = fmaxf(sMxS[(h * 2 + 0) * 64 + r], sMxS[(h * 2 + 1) * 64 + r]);
    if (!diag){
      posB[(size_t)bm * BS + Rn + t] = fminf(sMnT[(h * 2 + 0) * 64 + r], sMnT[(h * 2 + 1) * 64 + r]);
      negB[(size_t)bm * BS + Rn + t] = fmaxf(sMxT[(h * 2 + 0) * 64 + r], sMxT[(h * 2 + 1) * 64 + r]);
    }
  }
}

// ---- K2: reduce bound partials 32 -> 1 -----------------------------------
__global__ void k_redbounds(const float* __restrict__ posB, const float* __restrict__ negB,
                            float* __restrict__ pos_bound, float* __restrict__ neg_bound){
  const int r = blockIdx.x * 256 + threadIdx.x;   // 16 blocks x 256
  float mn = __builtin_inff(), mx = -__builtin_inff();
  #pragma unroll
  for (int s = 0; s < NSLOT; ++s){
    mn = fminf(mn, posB[(size_t)s * BS + r]);
    mx = fmaxf(mx, negB[(size_t)s * BS + r]);
  }
  pos_bound[r] = mn;            // empty class -> +inf (masks all-false, as ref)
  neg_bound[r] = mx;            // empty -> -inf
}

// ---- K3: GEMM + per-col sum-exp PARTIALS ---------------------------------
// SNp/SPp float[NSLOT][BS]; for col-tile c: slot s<=c by std of tile (s,c)
// (diag incl.), slot s>c by transposed of tile (c,s). Each written once.
__global__ __launch_bounds__(256)
void k_stats(const ushort* __restrict__ Xh, const int* __restrict__ labels,
             const float* __restrict__ pos_bound, const float* __restrict__ neg_bound,
             float* __restrict__ SNp, float* __restrict__ SPp)
{
  __shared__ ushort lds[4][BUF_USH];
  const int t = threadIdx.x;
  int Rm, Rn; bool diag;
  decode_tile((int)blockIdx.x, Rm, Rn, diag);
  const int bm = Rm >> 7, bn = Rn >> 7;

  f32x4 acc[4][4];
  gemm_tile_pipe(acc, lds, Xh, Rm, Rn, t);

  const int l  = t & 63;
  const int w  = t >> 6;
  const int wm = w >> 1, wn = w & 1;
  const int lc = l & 15, lq = l >> 4;

  int labr[4][4];
  #pragma unroll
  for (int fm = 0; fm < 4; ++fm)
    #pragma unroll
    for (int v = 0; v < 4; ++v)
      labr[fm][v] = labels[Rm + wm * 64 + fm * 16 + lq * 4 + v];

  __syncthreads();
  float* sSNs = (float*)&lds[0][0];   // [wn][wm][c64] std
  float* sSPs = sSNs + 256;
  float* sSNt = sSNs + 512;           // [wm][wn][r64] transposed
  float* sSPt = sSNs + 768;

  // std: stats for cols of Rn-block, reduced over this wave's 64 rows
  #pragma unroll
  for (int fn = 0; fn < 4; ++fn){
    const int gc = Rn + wn * 64 + fn * 16 + lc;
    const int labc = labels[gc];
    const float pb = pos_bound[gc];
    const float nb = neg_bound[gc];
    float sN = 0.f, sP = 0.f;
    #pragma unroll
    for (int fm = 0; fm < 4; ++fm)
      #pragma unroll
      for (int v = 0; v < 4; ++v){
        const float s = acc[fm][fn][v];
        const bool same = (labc == labr[fm][v]);
        sN += ((!same) && (s + 0.1f > pb)) ? __expf(40.0f * (s - 0.5f)) : 0.0f;
        sP += (same && (s - 0.1f < nb))    ? __expf(-2.0f * (s - 0.5f)) : 0.0f;
      }
    #pragma unroll
    for (int off = 16; off < 64; off <<= 1){
      sN += __shfl_xor(sN, off);
      sP += __shfl_xor(sP, off);
    }
    if (l < 16){
      const int c64 = fn * 16 + lc;
      sSNs[(wn * 2 + wm) * 64 + c64] = sN;
      sSPs[(wn * 2 + wm) * 64 + c64] = sP;
    }
  }
  if (!diag){
    // transposed: stats for cols == this tile's row indices
    #pragma unroll
    for (int fm = 0; fm < 4; ++fm){
      float pbr[4], nbr[4];
      #pragma unroll
      for (int v = 0; v < 4; ++v){
        const int grow = Rm + wm * 64 + fm * 16 + lq * 4 + v;
        pbr[v] = pos_bound[grow];
        nbr[v] = neg_bound[grow];
      }
      float sN[4] = {0.f, 0.f, 0.f, 0.f}, sP[4] = {0.f, 0.f, 0.f, 0.f};
      #pragma unroll
      for (int fn = 0; fn < 4; ++fn){
        const int gc = Rn + wn * 64 + fn * 16 + lc;
        const int labc = labels[gc];
        #pragma unroll
        for (int v = 0; v < 4; ++v){
          const float s = acc[fm][fn][v];
          const bool same = (labc == labr[fm][v]);
          sN[v] += ((!same) && (s + 0.1f > pbr[v])) ? __expf(40.0f * (s - 0.5f)) : 0.0f;
          sP[v] += (same && (s - 0.1f < nbr[v]))    ? __expf(-2.0f * (s - 0.5f)) : 0.0f;
        }
      }
      #pragma unroll
      for (int off = 1; off < 16; off <<= 1)
        #pragma unroll
        for (int v = 0; v < 4; ++v){
          sN[v] += __shfl_xor(sN[v], off);
          sP[v] += __shfl_xor(sP[v], off);
        }
      if (lc == 0){
        #pragma unroll
        for (int v = 0; v < 4; ++v){
          const int r64 = fm * 16 + lq * 4 + v;
          sSNt[(wm * 2 + wn) * 64 + r64] = sN[v];
          sSPt[(wm * 2 + wn) * 64 + r64] = sP[v];
        }
      }
    }
  }
  __syncthreads();
  if (t < 128){
    const int h = t >> 6, r = t & 63;
    SNp[(size_t)bm * BS + Rn + t] = sSNs[(h * 2 + 0) * 64 + r] + sSNs[(h * 2 + 1) * 64 + r];
    SPp[(size_t)bm * BS + Rn + t] = sSPs[(h * 2 + 0) * 64 + r] + sSPs[(h * 2 + 1) * 64 + r];
    if (!diag){
      SNp[(size_t)bn * BS + Rm + t] = sSNt[(h * 2 + 0) * 64 + r] + sSNt[(h * 2 + 1) * 64 + r];
      SPp[(size_t)bn * BS + Rm + t] = sSPt[(h * 2 + 0) * 64 + r] + sSPt[(h * 2 + 1) * 64 + r];
    }
  }
}

// ---- K4a: reduce stat partials, 16 blocks -> 16 float4 -------------------
__global__ void k_redstats(const float* __restrict__ SNp, const float* __restrict__ SPp,
                           float4* __restrict__ part)
{
  const int t = threadIdx.x;
  const int c = blockIdx.x * 256 + t;             // 16 blocks x 256
  float sn = 0.f, sp = 0.f;
  #pragma unroll
  for (int s = 0; s < NSLOT; ++s){
    sn += SNp[(size_t)s * BS + c];
    sp += SPp[(size_t)s * BS + c];
  }
  float sumP = (sp != 0.f) ? log1pf(sp) : 0.f;    // softplus(log S) = log1p(S)
  float cP   = (sp != 0.f) ? 1.f : 0.f;           // nz == (S != 0)
  float sumN = (sn != 0.f) ? log1pf(sn) : 0.f;
  float cN   = (sn != 0.f) ? 1.f : 0.f;
  #pragma unroll
  for (int off = 32; off; off >>= 1){
    sumP += __shfl_down(sumP, off); cP += __shfl_down(cP, off);
    sumN += __shfl_down(sumN, off); cN += __shfl_down(cN, off);
  }
  __shared__ float red[4][4];
  const int w = t >> 6;
  if ((t & 63) == 0){ red[w][0] = sumP; red[w][1] = cP; red[w][2] = sumN; red[w][3] = cN; }
  __syncthreads();
  if (t == 0){
    float a = 0.f, b = 0.f, c2 = 0.f, d = 0.f;
    for (int i = 0; i < 4; ++i){ a += red[i][0]; b += red[i][1]; c2 += red[i][2]; d += red[i][3]; }
    part[blockIdx.x] = make_float4(a, b, c2, d);
  }
}

// ---- K4b: final scalar (single wave) -------------------------------------
__global__ void k_final2(const float4* __restrict__ part, float* __restrict__ out)
{
  const int l = threadIdx.x;                      // 64 threads
  float4 v = (l < 16) ? part[l] : make_float4(0.f, 0.f, 0.f, 0.f);
  float sumP = v.x, cP = v.y, sumN = v.z, cN = v.w;
  #pragma unroll
  for (int off = 8; off; off >>= 1){
    sumP += __shfl_down(sumP, off); cP += __shfl_down(cP, off);
    sumN += __shfl_down(sumN, off); cN += __shfl_down(cN, off);
  }
  if (l == 0){
    const float LN2 = 0.69314718055994531f;       // softplus(0)
    const float tP = (cP > 0.f) ? (sumP / 2.0f)  / fmaxf(cP, 1.f) : LN2 / 2.0f;
    const float tN = (cN > 0.f) ? (sumN / 40.0f) / fmaxf(cN, 1.f) : LN2 / 40.0f;
    out[0] = tP + tN;
  }
}

// ---- launch --------------------------------------------------------------
extern "C" void kernel_launch(void* const* d_in, const int* in_sizes, int n_in,
                              void* d_out, int out_size, void* d_ws, size_t ws_size,
                              hipStream_t stream) {
  const float* x    = (const float*)d_in[0];   // batch (4096x512 fp32)
  const int* labels = (const int*)d_in[1];     // int32 labels
  char* W = (char*)d_ws;
  // ws (~5.03 MB, all written-before-read, no memsets):
  //   Xh 4MB | P1 512KB (posB -> SNp) | P2 512KB (negB -> SPp)
  //   | pos_bound 16KB | neg_bound 16KB | part 256B
  ushort* Xh        = (ushort*)W;
  float*  P1        = (float*)(W + (4u << 20));
  float*  P2        = (float*)(W + (4u << 20) + (512u << 10));
  float*  pos_bound = (float*)(W + (5u << 20));
  float*  neg_bound = (float*)(W + (5u << 20) + (16u << 10));
  float4* part      = (float4*)(W + (5u << 20) + (32u << 10));

  k_convert<<<(BS * DIM / 4) / 256, 256, 0, stream>>>(x, Xh);
  k_bounds<<<NTILES, 256, 0, stream>>>(Xh, labels, P1, P2);
  k_redbounds<<<BS / 256, 256, 0, stream>>>(P1, P2, pos_bound, neg_bound);
  k_stats<<<NTILES, 256, 0, stream>>>(Xh, labels, pos_bound, neg_bound, P1, P2);
  k_redstats<<<BS / 256, 256, 0, stream>>>(P1, P2, part);
  k_final2<<<1, 64, 0, stream>>>(part, (float*)d_out);
}